// Round 11
// baseline (55.728 us; speedup 1.0000x reference)
//
#include <hip/hip_runtime.h>
#include <hip/hip_bf16.h>

typedef __attribute__((ext_vector_type(4))) float f32x4;
typedef __attribute__((ext_vector_type(8))) short short8;
typedef __attribute__((ext_vector_type(4))) unsigned short ushort4v;
typedef _Float16 f16x8 __attribute__((ext_vector_type(8)));

#define NB 8
#define NN 2048
#define NF 128
#define LOG2E 1.4426950408889634f
#define MASK_NEG_H -60000.0f

static __device__ __forceinline__ unsigned short f2bf(float f) {
    union { __hip_bfloat16 b; unsigned short u; } cv;
    cv.b = __float2bfloat16(f);
    return cv.u;
}

// ---------------------------------------------------------------------------
// Kernel PRE (fused): blocks 0..255 = hprime (h@W -> vfrag B-frags, si/sj);
// blocks 256..1279 = bias -> biasF A-frags (fp16).
// ---------------------------------------------------------------------------
__global__ __launch_bounds__(256) void k_pre(
    const float* __restrict__ h, const int* __restrict__ adj,
    const float* __restrict__ dist, const float* __restrict__ W,
    const float* __restrict__ a, const float* __restrict__ scaler,
    unsigned short* __restrict__ vfrag, float* __restrict__ siC,
    float* __restrict__ sjC, _Float16* __restrict__ biasF)
{
    __shared__ __align__(16) unsigned char smem[34816];
    const int bid = blockIdx.x;
    const int t = threadIdx.x;

    if (bid < 256) {
        // ================= hprime =================
        unsigned char* WT = smem;                  // 32KB swizzled W^T bf16
        float* wa1 = (float*)(smem + 32768);
        float* wa2 = wa1 + NF;

        const int lane = t & 63;
        const int w = t >> 6;
        const int b = bid >> 5;
        const int i0 = (bid & 31) << 6;

        {
            const int f = t >> 1;
            const int c0 = (t & 1) << 6;
            float s1 = 0.f, s2 = 0.f;
            const float* wrow = W + f * NF + c0;
            const float* a1p = a + c0;
            const float* a2p = a + NF + c0;
            #pragma unroll 8
            for (int c = 0; c < 64; ++c) {
                float wv = wrow[c];
                s1 += wv * a1p[c];
                s2 += wv * a2p[c];
                int col = c0 + c;
                int dst = col * 256 + ((2 * f) ^ ((col & 15) << 4));
                *reinterpret_cast<unsigned short*>(&WT[dst]) = f2bf(wv);
            }
            s1 += __shfl_xor(s1, 1);
            s2 += __shfl_xor(s2, 1);
            if ((t & 1) == 0) { wa1[f] = s1 * LOG2E; wa2[f] = s2 * LOG2E; }
        }
        __syncthreads();

        const int l15 = lane & 15;
        const int arow = i0 + w * 16 + l15;
        const int kofs = (lane >> 4) << 3;
        const float* hrow = h + (size_t)(b * NN + arow) * NF + kofs;
        const int swz = l15 << 4;

        f32x4 acc[8];
        #pragma unroll
        for (int nt = 0; nt < 8; ++nt) acc[nt] = (f32x4)(0.f);
        float s1 = 0.f, s2 = 0.f;

        #pragma unroll
        for (int k0 = 0; k0 < NF; k0 += 32) {
            f32x4 h0 = *reinterpret_cast<const f32x4*>(hrow + k0);
            f32x4 h1 = *reinterpret_cast<const f32x4*>(hrow + k0 + 4);
            f32x4 w1lo = *reinterpret_cast<const f32x4*>(&wa1[k0 + kofs]);
            f32x4 w1hi = *reinterpret_cast<const f32x4*>(&wa1[k0 + kofs + 4]);
            f32x4 w2lo = *reinterpret_cast<const f32x4*>(&wa2[k0 + kofs]);
            f32x4 w2hi = *reinterpret_cast<const f32x4*>(&wa2[k0 + kofs + 4]);
            short8 af;
            #pragma unroll
            for (int e = 0; e < 4; ++e) {
                s1 += h0[e] * w1lo[e] + h1[e] * w1hi[e];
                s2 += h0[e] * w2lo[e] + h1[e] * w2hi[e];
                af[e]     = (short)f2bf(h0[e]);
                af[4 + e] = (short)f2bf(h1[e]);
            }
            const int ib = (2 * (k0 + kofs)) ^ swz;
            #pragma unroll
            for (int nt = 0; nt < 8; ++nt) {
                short8 bf8 = *reinterpret_cast<short8*>(&WT[(nt * 16 + l15) * 256 + ib]);
                acc[nt] = __builtin_amdgcn_mfma_f32_16x16x32_bf16(af, bf8, acc[nt], 0, 0, 0);
            }
        }

        s1 += __shfl_xor(s1, 16); s1 += __shfl_xor(s1, 32);
        s2 += __shfl_xor(s2, 16); s2 += __shfl_xor(s2, 32);
        if (lane < 16) {
            siC[b * NN + arow] = s1;
            sjC[b * NN + arow] = s2;
        }

        const int J0 = i0 + w * 16 + ((lane >> 4) << 2);
        const int s = J0 >> 5;
        const int jq = (J0 >> 3) & 3;
        const int eh = J0 & 7;
        #pragma unroll
        for (int nt = 0; nt < 8; ++nt) {
            ushort4v pk;
            #pragma unroll
            for (int e = 0; e < 4; ++e) pk[e] = f2bf(acc[nt][e]);
            *reinterpret_cast<ushort4v*>(
                vfrag + (((size_t)(b * 64 + s) * 8 + nt) * 64 + (l15 | (jq << 4))) * 8 + eh) = pk;
        }
    } else {
        // ================= bias =================
        _Float16 (*st)[64][8] = (_Float16 (*)[64][8])smem;   // 8KB
        const int bid2 = bid - 256;
        const int iblk = bid2 >> 3;
        const int jch = bid2 & 7;
        const int i_l = t >> 4;
        const int o2 = t & 15;
        const int i = iblk * 16 + i_l;
        const int jbase = jch * 256 + o2 * 16;
        const float sc = scaler[0];

        const int* ap = adj + (size_t)i * NN + jbase;
        const float* dp = dist + (size_t)i * NN + jbase;
        int av[16]; float dv[16];
        *reinterpret_cast<int4*>(&av[0])  = *reinterpret_cast<const int4*>(ap);
        *reinterpret_cast<int4*>(&av[4])  = *reinterpret_cast<const int4*>(ap + 4);
        *reinterpret_cast<int4*>(&av[8])  = *reinterpret_cast<const int4*>(ap + 8);
        *reinterpret_cast<int4*>(&av[12]) = *reinterpret_cast<const int4*>(ap + 12);
        *reinterpret_cast<float4*>(&dv[0])  = *reinterpret_cast<const float4*>(dp);
        *reinterpret_cast<float4*>(&dv[4])  = *reinterpret_cast<const float4*>(dp + 4);
        *reinterpret_cast<float4*>(&dv[8])  = *reinterpret_cast<const float4*>(dp + 8);
        *reinterpret_cast<float4*>(&dv[12]) = *reinterpret_cast<const float4*>(dp + 12);

        #pragma unroll
        for (int u = 0; u < 2; ++u) {
            const int sl = (o2 * 2 + u) >> 2;
            const int jq = (o2 * 2 + u) & 3;
            f16x8 pk;
            #pragma unroll
            for (int e = 0; e < 8; ++e) {
                const int idx = u * 8 + e;
                float v = (av[idx] > 0) ? (-__log2f(dv[idx] + 1e-6f) * sc) : MASK_NEG_H;
                pk[e] = (_Float16)v;
            }
            *reinterpret_cast<f16x8*>(&st[sl][i_l | (jq << 4)][0]) = pk;
        }
        __syncthreads();

        const int w = t >> 6, lane = t & 63;
        #pragma unroll
        for (int sub = 0; sub < 2; ++sub) {
            const int fs = w * 2 + sub;
            *reinterpret_cast<f16x8*>(
                biasF + ((size_t)(iblk * 64 + jch * 8 + fs) * 64 + lane) * 8) =
                *reinterpret_cast<f16x8*>(&st[fs][lane][0]);
        }
    }
}

// ---------------------------------------------------------------------------
// Kernel C: barrier-free main loop; wave = 32 rows (2 A-frag rowsets) x all
// 128 cols x 256-j strip -> every V-frag load feeds 2 MFMAs, halving the
// dominant per-CU L1/VMEM stream (V: 2MB -> 1MB per CU).
// Block = 512 thr = 8 jq-waves over a 32-row group; grid = 8b x 64rg = 512
// = 2 blocks/CU, 16 waves/CU. acc[2][8]=64 VGPR (~114 total, cap 128).
// Tail: 5-barrier tree over 8 jq partials (64KB LDS) + 1-wave epilogue.
// XCD = batch: V[b] (512KB) L2-pinned; bias streams.
// ---------------------------------------------------------------------------
__global__ __launch_bounds__(512, 4) void k_attn(
    const unsigned short* __restrict__ vfrag, const float* __restrict__ siC,
    const float* __restrict__ sjC, const _Float16* __restrict__ biasF,
    float* __restrict__ out)
{
    __shared__ __align__(16) f32x4 red[4][1024];   // 4 x 16KB = 64KB
    __shared__ float lp[8][2][16];                 // 1KB

    const int t = threadIdx.x;
    const int lane = t & 63;
    const int jq = t >> 6;         // 0..7, 256-j strip
    const int l15 = lane & 15;
    const int hi = lane >> 4;

    const int b = blockIdx.x & 7;   // XCD = batch
    const int rg = blockIdx.x >> 3; // 32-row group 0..63

    const int rowbase = rg * 32;
    const float si0 = siC[b * NN + rowbase + l15];
    const float si1 = siC[b * NN + rowbase + 16 + l15];

    const float* sjp = sjC + b * NN + jq * 256 + hi * 8;
    const _Float16* bp0 = biasF + ((size_t)(rg * 2 * 64 + jq * 8) * 64 + lane) * 8;
    const _Float16* bp1 = bp0 + 32768;   // iblk+1 (64*64*8)
    const unsigned short* vp = vfrag +
        ((size_t)(b * 64 + jq * 8) * 8) * 512 + lane * 8;

    f32x4 acc[2][8];
    #pragma unroll
    for (int rs = 0; rs < 2; ++rs)
        #pragma unroll
        for (int ct = 0; ct < 8; ++ct) acc[rs][ct] = (f32x4)(0.f);
    float ls0 = 0.f, ls1 = 0.f;

    #pragma unroll 2
    for (int sl = 0; sl < 8; ++sl) {
        f32x4 sj0 = *reinterpret_cast<const f32x4*>(sjp + sl * 32);
        f32x4 sj1 = *reinterpret_cast<const f32x4*>(sjp + sl * 32 + 4);
        f16x8 bv0 = *reinterpret_cast<const f16x8*>(bp0 + sl * 512);
        f16x8 bv1 = *reinterpret_cast<const f16x8*>(bp1 + sl * 512);
        short8 pa0, pa1;
        #pragma unroll
        for (int e = 0; e < 8; ++e) {
            const float sjv = (e < 4) ? sj0[e] : sj1[e - 4];
            float x0 = si0 + sjv;
            x0 = fmaxf(x0, 0.2f * x0) + (float)bv0[e];
            float p0 = __builtin_amdgcn_exp2f(x0);
            ls0 += p0;
            pa0[e] = (short)f2bf(p0);
            float x1 = si1 + sjv;
            x1 = fmaxf(x1, 0.2f * x1) + (float)bv1[e];
            float p1 = __builtin_amdgcn_exp2f(x1);
            ls1 += p1;
            pa1[e] = (short)f2bf(p1);
        }
        const unsigned short* vs = vp + sl * 4096;
        #pragma unroll
        for (int ct = 0; ct < 8; ++ct) {
            const short8 bfr = *reinterpret_cast<const short8*>(vs + ct * 512);
            acc[0][ct] = __builtin_amdgcn_mfma_f32_16x16x32_bf16(pa0, bfr, acc[0][ct], 0, 0, 0);
            acc[1][ct] = __builtin_amdgcn_mfma_f32_16x16x32_bf16(pa1, bfr, acc[1][ct], 0, 0, 0);
        }
    }

    ls0 += __shfl_xor(ls0, 16); ls0 += __shfl_xor(ls0, 32);
    ls1 += __shfl_xor(ls1, 16); ls1 += __shfl_xor(ls1, 32);
    if (lane < 16) { lp[jq][0][l15] = ls0; lp[jq][1][l15] = ls1; }

    #define WACC(buf) { _Pragma("unroll") for (int rs = 0; rs < 2; ++rs)      \
        _Pragma("unroll") for (int ct = 0; ct < 8; ++ct)                      \
        red[buf][(rs * 8 + ct) * 64 + lane] = acc[rs][ct]; }
    #define AACC(buf) { _Pragma("unroll") for (int rs = 0; rs < 2; ++rs)      \
        _Pragma("unroll") for (int ct = 0; ct < 8; ++ct)                      \
        acc[rs][ct] += red[buf][(rs * 8 + ct) * 64 + lane]; }

    if (jq & 1) WACC(jq >> 1)
    __syncthreads();
    if (!(jq & 1)) AACC(jq >> 1)
    __syncthreads();
    if (jq == 2) WACC(0)
    if (jq == 6) WACC(1)
    __syncthreads();
    if (jq == 0) AACC(0)
    if (jq == 4) AACC(1)
    __syncthreads();
    if (jq == 4) WACC(0)
    __syncthreads();
    if (jq == 0) {
        AACC(0)
        float linv0[4], linv1[4];
        #pragma unroll
        for (int e = 0; e < 4; ++e) {
            const int rr = (hi << 2) + e;
            float t0 = 0.f, t1 = 0.f;
            #pragma unroll
            for (int q = 0; q < 8; ++q) { t0 += lp[q][0][rr]; t1 += lp[q][1][rr]; }
            linv0[e] = 1.0f / t0;
            linv1[e] = 1.0f / t1;
        }
        #pragma unroll
        for (int ct = 0; ct < 8; ++ct) {
            const int col = ct * 16 + l15;
            #pragma unroll
            for (int e = 0; e < 4; ++e) {
                const int r0 = rowbase + (hi << 2) + e;
                float v0 = acc[0][ct][e] * linv0[e];
                v0 = (v0 > 0.f) ? v0 : expm1f(v0);
                out[(size_t)(b * NN + r0) * NF + col] = v0;
                float v1 = acc[1][ct][e] * linv1[e];
                v1 = (v1 > 0.f) ? v1 : expm1f(v1);
                out[(size_t)(b * NN + r0 + 16) * NF + col] = v1;
            }
        }
    }
    #undef WACC
    #undef AACC
}

extern "C" void kernel_launch(void* const* d_in, const int* in_sizes, int n_in,
                              void* d_out, int out_size, void* d_ws, size_t ws_size,
                              hipStream_t stream) {
    (void)in_sizes; (void)n_in; (void)out_size; (void)ws_size;
    const float* h      = (const float*)d_in[0];
    const int*   adj    = (const int*)d_in[1];
    const float* dist   = (const float*)d_in[2];
    const float* W      = (const float*)d_in[3];
    const float* a      = (const float*)d_in[4];
    const float* scaler = (const float*)d_in[5];
    float* out = (float*)d_out;

    char* ws = (char*)d_ws;
    unsigned short* vfrag = (unsigned short*)ws;                     // 4 MiB
    float* siC      = (float*)(ws + 4 * 1024 * 1024);                // 64 KiB
    float* sjC      = (float*)(ws + 4 * 1024 * 1024 + 65536);        // 64 KiB
    _Float16* biasF = (_Float16*)(ws + 4 * 1024 * 1024 + 2 * 65536); // 8 MiB

    k_pre<<<dim3(1280), dim3(256), 0, stream>>>(h, adj, dist, W, a, scaler,
                                                vfrag, siC, sjC, biasF);
    k_attn<<<dim3(NB * NN / 32), dim3(512), 0, stream>>>(vfrag, siC, sjC, biasF, out);
}

// Round 12
// 52.467 us; speedup vs baseline: 1.0622x; 1.0622x over previous
//
#include <hip/hip_runtime.h>
#include <hip/hip_bf16.h>

typedef __attribute__((ext_vector_type(4))) float f32x4;
typedef __attribute__((ext_vector_type(8))) short short8;
typedef __attribute__((ext_vector_type(4))) unsigned short ushort4v;
typedef _Float16 f16x8 __attribute__((ext_vector_type(8)));

#define NB 8
#define NN 2048
#define NF 128
#define LOG2E 1.4426950408889634f
#define MASK_NEG_H -60000.0f

static __device__ __forceinline__ unsigned short f2bf(float f) {
    union { __hip_bfloat16 b; unsigned short u; } cv;
    cv.b = __float2bfloat16(f);
    return cv.u;
}

// ---------------------------------------------------------------------------
// Kernel PRE (fused): blocks 0..255 = hprime (h@W -> vfrag B-frags, si/sj);
// blocks 256..1279 = bias -> biasF A-frags (fp16).
// ---------------------------------------------------------------------------
__global__ __launch_bounds__(256) void k_pre(
    const float* __restrict__ h, const int* __restrict__ adj,
    const float* __restrict__ dist, const float* __restrict__ W,
    const float* __restrict__ a, const float* __restrict__ scaler,
    unsigned short* __restrict__ vfrag, float* __restrict__ siC,
    float* __restrict__ sjC, _Float16* __restrict__ biasF)
{
    __shared__ __align__(16) unsigned char smem[34816];
    const int bid = blockIdx.x;
    const int t = threadIdx.x;

    if (bid < 256) {
        // ================= hprime =================
        unsigned char* WT = smem;                  // 32KB swizzled W^T bf16
        float* wa1 = (float*)(smem + 32768);
        float* wa2 = wa1 + NF;

        const int lane = t & 63;
        const int w = t >> 6;
        const int b = bid >> 5;
        const int i0 = (bid & 31) << 6;

        {
            const int f = t >> 1;
            const int c0 = (t & 1) << 6;
            float s1 = 0.f, s2 = 0.f;
            const float* wrow = W + f * NF + c0;
            const float* a1p = a + c0;
            const float* a2p = a + NF + c0;
            #pragma unroll 8
            for (int c = 0; c < 64; ++c) {
                float wv = wrow[c];
                s1 += wv * a1p[c];
                s2 += wv * a2p[c];
                int col = c0 + c;
                int dst = col * 256 + ((2 * f) ^ ((col & 15) << 4));
                *reinterpret_cast<unsigned short*>(&WT[dst]) = f2bf(wv);
            }
            s1 += __shfl_xor(s1, 1);
            s2 += __shfl_xor(s2, 1);
            if ((t & 1) == 0) { wa1[f] = s1 * LOG2E; wa2[f] = s2 * LOG2E; }
        }
        __syncthreads();

        const int l15 = lane & 15;
        const int arow = i0 + w * 16 + l15;
        const int kofs = (lane >> 4) << 3;
        const float* hrow = h + (size_t)(b * NN + arow) * NF + kofs;
        const int swz = l15 << 4;

        f32x4 acc[8];
        #pragma unroll
        for (int nt = 0; nt < 8; ++nt) acc[nt] = (f32x4)(0.f);
        float s1 = 0.f, s2 = 0.f;

        #pragma unroll
        for (int k0 = 0; k0 < NF; k0 += 32) {
            f32x4 h0 = *reinterpret_cast<const f32x4*>(hrow + k0);
            f32x4 h1 = *reinterpret_cast<const f32x4*>(hrow + k0 + 4);
            f32x4 w1lo = *reinterpret_cast<const f32x4*>(&wa1[k0 + kofs]);
            f32x4 w1hi = *reinterpret_cast<const f32x4*>(&wa1[k0 + kofs + 4]);
            f32x4 w2lo = *reinterpret_cast<const f32x4*>(&wa2[k0 + kofs]);
            f32x4 w2hi = *reinterpret_cast<const f32x4*>(&wa2[k0 + kofs + 4]);
            short8 af;
            #pragma unroll
            for (int e = 0; e < 4; ++e) {
                s1 += h0[e] * w1lo[e] + h1[e] * w1hi[e];
                s2 += h0[e] * w2lo[e] + h1[e] * w2hi[e];
                af[e]     = (short)f2bf(h0[e]);
                af[4 + e] = (short)f2bf(h1[e]);
            }
            const int ib = (2 * (k0 + kofs)) ^ swz;
            #pragma unroll
            for (int nt = 0; nt < 8; ++nt) {
                short8 bf8 = *reinterpret_cast<short8*>(&WT[(nt * 16 + l15) * 256 + ib]);
                acc[nt] = __builtin_amdgcn_mfma_f32_16x16x32_bf16(af, bf8, acc[nt], 0, 0, 0);
            }
        }

        s1 += __shfl_xor(s1, 16); s1 += __shfl_xor(s1, 32);
        s2 += __shfl_xor(s2, 16); s2 += __shfl_xor(s2, 32);
        if (lane < 16) {
            siC[b * NN + arow] = s1;
            sjC[b * NN + arow] = s2;
        }

        const int J0 = i0 + w * 16 + ((lane >> 4) << 2);
        const int s = J0 >> 5;
        const int jq = (J0 >> 3) & 3;
        const int eh = J0 & 7;
        #pragma unroll
        for (int nt = 0; nt < 8; ++nt) {
            ushort4v pk;
            #pragma unroll
            for (int e = 0; e < 4; ++e) pk[e] = f2bf(acc[nt][e]);
            *reinterpret_cast<ushort4v*>(
                vfrag + (((size_t)(b * 64 + s) * 8 + nt) * 64 + (l15 | (jq << 4))) * 8 + eh) = pk;
        }
    } else {
        // ================= bias =================
        _Float16 (*st)[64][8] = (_Float16 (*)[64][8])smem;   // 8KB
        const int bid2 = bid - 256;
        const int iblk = bid2 >> 3;
        const int jch = bid2 & 7;
        const int i_l = t >> 4;
        const int o2 = t & 15;
        const int i = iblk * 16 + i_l;
        const int jbase = jch * 256 + o2 * 16;
        const float sc = scaler[0];

        const int* ap = adj + (size_t)i * NN + jbase;
        const float* dp = dist + (size_t)i * NN + jbase;
        int av[16]; float dv[16];
        *reinterpret_cast<int4*>(&av[0])  = *reinterpret_cast<const int4*>(ap);
        *reinterpret_cast<int4*>(&av[4])  = *reinterpret_cast<const int4*>(ap + 4);
        *reinterpret_cast<int4*>(&av[8])  = *reinterpret_cast<const int4*>(ap + 8);
        *reinterpret_cast<int4*>(&av[12]) = *reinterpret_cast<const int4*>(ap + 12);
        *reinterpret_cast<float4*>(&dv[0])  = *reinterpret_cast<const float4*>(dp);
        *reinterpret_cast<float4*>(&dv[4])  = *reinterpret_cast<const float4*>(dp + 4);
        *reinterpret_cast<float4*>(&dv[8])  = *reinterpret_cast<const float4*>(dp + 8);
        *reinterpret_cast<float4*>(&dv[12]) = *reinterpret_cast<const float4*>(dp + 12);

        #pragma unroll
        for (int u = 0; u < 2; ++u) {
            const int sl = (o2 * 2 + u) >> 2;
            const int jq = (o2 * 2 + u) & 3;
            f16x8 pk;
            #pragma unroll
            for (int e = 0; e < 8; ++e) {
                const int idx = u * 8 + e;
                float v = (av[idx] > 0) ? (-__log2f(dv[idx] + 1e-6f) * sc) : MASK_NEG_H;
                pk[e] = (_Float16)v;
            }
            *reinterpret_cast<f16x8*>(&st[sl][i_l | (jq << 4)][0]) = pk;
        }
        __syncthreads();

        const int w = t >> 6, lane = t & 63;
        #pragma unroll
        for (int sub = 0; sub < 2; ++sub) {
            const int fs = w * 2 + sub;
            *reinterpret_cast<f16x8*>(
                biasF + ((size_t)(iblk * 64 + jch * 8 + fs) * 64 + lane) * 8) =
                *reinterpret_cast<f16x8*>(&st[fs][lane][0]);
        }
    }
}

// ---------------------------------------------------------------------------
// Kernel C: V streamed through LDS, double-buffered, T14 issue-early/
// write-late. Block = 64 rows x 128 cols x full j; grid 256 (1/CU),
// XCD = batch -> V[b] (512KB) L2-pinned. 8 waves = 4 rt (16-row tiles) x
// 2 jh (64-j halves of each 128-j tile). 16 tiles x 32KB V, 1 barrier/tile.
// All V MFMA reads are LDS b128; bias/sj stream from L2 into registers.
// ---------------------------------------------------------------------------
__global__ __launch_bounds__(512, 4) void k_attn(
    const unsigned short* __restrict__ vfrag, const float* __restrict__ siC,
    const float* __restrict__ sjC, const _Float16* __restrict__ biasF,
    float* __restrict__ out)
{
    __shared__ __align__(16) unsigned char vt[2][32768];  // V tile dbuf
    __shared__ float lp[2][4][16];                        // 512B

    const int t = threadIdx.x;
    const int lane = t & 63;
    const int w = t >> 6;          // 0..7
    const int rt = w & 3;          // 16-row tile
    const int jh = w >> 2;         // 64-j half of the 128-j tile
    const int l15 = lane & 15;
    const int hi = lane >> 4;

    const int b = blockIdx.x & 7;   // XCD = batch
    const int rg = blockIdx.x >> 3; // 64-row group 0..31

    const int rowbase = rg * 64 + rt * 16;
    const float si0 = siC[b * NN + rowbase + l15];

    // staging: 4 chunks of 16B per thread per 32KB tile (tile = 16384 shorts)
    const unsigned short* vsrc = vfrag + (size_t)b * 64 * 4096 + t * 8;
    const int dofs = t * 16;

    // per-wave pointers (s-slot s = tile*4 + jh*2 + q)
    const _Float16* bp = biasF + ((size_t)((rg * 4 + rt) * 64) * 64 + lane) * 8;
    const float* sjb = sjC + b * NN + hi * 8;

    f32x4 acc[8];
    #pragma unroll
    for (int ct = 0; ct < 8; ++ct) acc[ct] = (f32x4)(0.f);
    float ls0 = 0.f;

    // prologue: stage tile 0
    {
        short8 v0 = *reinterpret_cast<const short8*>(vsrc);
        short8 v1 = *reinterpret_cast<const short8*>(vsrc + 4096);
        short8 v2 = *reinterpret_cast<const short8*>(vsrc + 8192);
        short8 v3 = *reinterpret_cast<const short8*>(vsrc + 12288);
        *reinterpret_cast<short8*>(&vt[0][dofs])         = v0;
        *reinterpret_cast<short8*>(&vt[0][dofs + 8192])  = v1;
        *reinterpret_cast<short8*>(&vt[0][dofs + 16384]) = v2;
        *reinterpret_cast<short8*>(&vt[0][dofs + 24576]) = v3;
    }
    __syncthreads();

    for (int tl = 0; tl < 16; ++tl) {
        const int cur = tl & 1;
        // T14: issue next tile's loads BEFORE compute (latency hides under it)
        short8 v0, v1, v2, v3;
        if (tl < 15) {
            const unsigned short* ns = vsrc + (tl + 1) * 16384;
            v0 = *reinterpret_cast<const short8*>(ns);
            v1 = *reinterpret_cast<const short8*>(ns + 4096);
            v2 = *reinterpret_cast<const short8*>(ns + 8192);
            v3 = *reinterpret_cast<const short8*>(ns + 12288);
        }
        // compute current tile: 2 s-slots (32 j each) x 8 ct MFMAs
        #pragma unroll
        for (int q = 0; q < 2; ++q) {
            const int s = tl * 4 + jh * 2 + q;
            f32x4 sj0 = *reinterpret_cast<const f32x4*>(sjb + s * 32);
            f32x4 sj1 = *reinterpret_cast<const f32x4*>(sjb + s * 32 + 4);
            f16x8 bv = *reinterpret_cast<const f16x8*>(bp + s * 512);
            short8 pa;
            #pragma unroll
            for (int e = 0; e < 8; ++e) {
                const float sjv = (e < 4) ? sj0[e] : sj1[e - 4];
                float x = si0 + sjv;
                x = fmaxf(x, 0.2f * x) + (float)bv[e];
                float p = __builtin_amdgcn_exp2f(x);
                ls0 += p;
                pa[e] = (short)f2bf(p);
            }
            const int lsl = jh * 2 + q;     // s-slot within tile 0..3
            #pragma unroll
            for (int ct = 0; ct < 8; ++ct) {
                const short8 bfr = *reinterpret_cast<const short8*>(
                    &vt[cur][(lsl * 8 + ct) * 1024 + lane * 16]);
                acc[ct] = __builtin_amdgcn_mfma_f32_16x16x32_bf16(pa, bfr, acc[ct], 0, 0, 0);
            }
        }
        // write-late: next tile into other buffer, then one barrier
        if (tl < 15) {
            unsigned char* db = &vt[cur ^ 1][dofs];
            *reinterpret_cast<short8*>(db)          = v0;
            *reinterpret_cast<short8*>(db + 8192)   = v1;
            *reinterpret_cast<short8*>(db + 16384)  = v2;
            *reinterpret_cast<short8*>(db + 24576)  = v3;
        }
        __syncthreads();
    }

    // ---- combine jh halves ----
    ls0 += __shfl_xor(ls0, 16);
    ls0 += __shfl_xor(ls0, 32);
    if (lane < 16) lp[jh][rt][l15] = ls0;

    if (jh == 1) {
        #pragma unroll
        for (int ct = 0; ct < 8; ++ct)
            *reinterpret_cast<f32x4*>(&vt[0][(rt * 8 + ct) * 1024 + lane * 16]) = acc[ct];
    }
    __syncthreads();
    if (jh == 0) {
        float linv[4];
        #pragma unroll
        for (int e = 0; e < 4; ++e) {
            const int rr = (hi << 2) + e;
            linv[e] = 1.0f / (lp[0][rt][rr] + lp[1][rt][rr]);
        }
        #pragma unroll
        for (int ct = 0; ct < 8; ++ct) {
            f32x4 o = acc[ct] + *reinterpret_cast<const f32x4*>(
                &vt[0][(rt * 8 + ct) * 1024 + lane * 16]);
            const int col = ct * 16 + l15;
            #pragma unroll
            for (int e = 0; e < 4; ++e) {
                const int row = rowbase + (hi << 2) + e;
                float v = o[e] * linv[e];
                v = (v > 0.f) ? v : expm1f(v);
                out[(size_t)(b * NN + row) * NF + col] = v;
            }
        }
    }
}

extern "C" void kernel_launch(void* const* d_in, const int* in_sizes, int n_in,
                              void* d_out, int out_size, void* d_ws, size_t ws_size,
                              hipStream_t stream) {
    (void)in_sizes; (void)n_in; (void)out_size; (void)ws_size;
    const float* h      = (const float*)d_in[0];
    const int*   adj    = (const int*)d_in[1];
    const float* dist   = (const float*)d_in[2];
    const float* W      = (const float*)d_in[3];
    const float* a      = (const float*)d_in[4];
    const float* scaler = (const float*)d_in[5];
    float* out = (float*)d_out;

    char* ws = (char*)d_ws;
    unsigned short* vfrag = (unsigned short*)ws;                     // 4 MiB
    float* siC      = (float*)(ws + 4 * 1024 * 1024);                // 64 KiB
    float* sjC      = (float*)(ws + 4 * 1024 * 1024 + 65536);        // 64 KiB
    _Float16* biasF = (_Float16*)(ws + 4 * 1024 * 1024 + 2 * 65536); // 8 MiB

    k_pre<<<dim3(1280), dim3(256), 0, stream>>>(h, adj, dist, W, a, scaler,
                                                vfrag, siC, sjC, biasF);
    k_attn<<<dim3(NB * NN / 64), dim3(512), 0, stream>>>(vfrag, siC, sjC, biasF, out);
}

// Round 13
// 48.669 us; speedup vs baseline: 1.1451x; 1.0780x over previous
//
#include <hip/hip_runtime.h>
#include <hip/hip_bf16.h>

typedef __attribute__((ext_vector_type(4))) float f32x4;
typedef __attribute__((ext_vector_type(8))) short short8;
typedef __attribute__((ext_vector_type(4))) unsigned short ushort4v;
typedef _Float16 f16x8 __attribute__((ext_vector_type(8)));

#define NB 8
#define NN 2048
#define NF 128
#define LOG2E 1.4426950408889634f
#define MASK_NEG_H -60000.0f

static __device__ __forceinline__ unsigned short f2bf(float f) {
    union { __hip_bfloat16 b; unsigned short u; } cv;
    cv.b = __float2bfloat16(f);
    return cv.u;
}

// ---------------------------------------------------------------------------
// Kernel PRE (fused): blocks 0..255 = hprime (h@W -> vfrag B-frags bf16,
// siC fp32, sjH fp16); blocks 256..1279 = bias -> biasF A-frags (fp16).
// ---------------------------------------------------------------------------
__global__ __launch_bounds__(256) void k_pre(
    const float* __restrict__ h, const int* __restrict__ adj,
    const float* __restrict__ dist, const float* __restrict__ W,
    const float* __restrict__ a, const float* __restrict__ scaler,
    unsigned short* __restrict__ vfrag, float* __restrict__ siC,
    _Float16* __restrict__ sjH, _Float16* __restrict__ biasF)
{
    __shared__ __align__(16) unsigned char smem[34816];
    const int bid = blockIdx.x;
    const int t = threadIdx.x;

    if (bid < 256) {
        // ================= hprime =================
        unsigned char* WT = smem;                  // 32KB swizzled W^T bf16
        float* wa1 = (float*)(smem + 32768);
        float* wa2 = wa1 + NF;

        const int lane = t & 63;
        const int w = t >> 6;
        const int b = bid >> 5;
        const int i0 = (bid & 31) << 6;

        {
            const int f = t >> 1;
            const int c0 = (t & 1) << 6;
            float s1 = 0.f, s2 = 0.f;
            const float* wrow = W + f * NF + c0;
            const float* a1p = a + c0;
            const float* a2p = a + NF + c0;
            #pragma unroll 8
            for (int c = 0; c < 64; ++c) {
                float wv = wrow[c];
                s1 += wv * a1p[c];
                s2 += wv * a2p[c];
                int col = c0 + c;
                int dst = col * 256 + ((2 * f) ^ ((col & 15) << 4));
                *reinterpret_cast<unsigned short*>(&WT[dst]) = f2bf(wv);
            }
            s1 += __shfl_xor(s1, 1);
            s2 += __shfl_xor(s2, 1);
            if ((t & 1) == 0) { wa1[f] = s1 * LOG2E; wa2[f] = s2 * LOG2E; }
        }
        __syncthreads();

        const int l15 = lane & 15;
        const int arow = i0 + w * 16 + l15;
        const int kofs = (lane >> 4) << 3;
        const float* hrow = h + (size_t)(b * NN + arow) * NF + kofs;
        const int swz = l15 << 4;

        f32x4 acc[8];
        #pragma unroll
        for (int nt = 0; nt < 8; ++nt) acc[nt] = (f32x4)(0.f);
        float s1 = 0.f, s2 = 0.f;

        #pragma unroll
        for (int k0 = 0; k0 < NF; k0 += 32) {
            f32x4 h0 = *reinterpret_cast<const f32x4*>(hrow + k0);
            f32x4 h1 = *reinterpret_cast<const f32x4*>(hrow + k0 + 4);
            f32x4 w1lo = *reinterpret_cast<const f32x4*>(&wa1[k0 + kofs]);
            f32x4 w1hi = *reinterpret_cast<const f32x4*>(&wa1[k0 + kofs + 4]);
            f32x4 w2lo = *reinterpret_cast<const f32x4*>(&wa2[k0 + kofs]);
            f32x4 w2hi = *reinterpret_cast<const f32x4*>(&wa2[k0 + kofs + 4]);
            short8 af;
            #pragma unroll
            for (int e = 0; e < 4; ++e) {
                s1 += h0[e] * w1lo[e] + h1[e] * w1hi[e];
                s2 += h0[e] * w2lo[e] + h1[e] * w2hi[e];
                af[e]     = (short)f2bf(h0[e]);
                af[4 + e] = (short)f2bf(h1[e]);
            }
            const int ib = (2 * (k0 + kofs)) ^ swz;
            #pragma unroll
            for (int nt = 0; nt < 8; ++nt) {
                short8 bf8 = *reinterpret_cast<short8*>(&WT[(nt * 16 + l15) * 256 + ib]);
                acc[nt] = __builtin_amdgcn_mfma_f32_16x16x32_bf16(af, bf8, acc[nt], 0, 0, 0);
            }
        }

        s1 += __shfl_xor(s1, 16); s1 += __shfl_xor(s1, 32);
        s2 += __shfl_xor(s2, 16); s2 += __shfl_xor(s2, 32);
        if (lane < 16) {
            siC[b * NN + arow] = s1;
            sjH[b * NN + arow] = (_Float16)s2;
        }

        const int J0 = i0 + w * 16 + ((lane >> 4) << 2);
        const int s = J0 >> 5;
        const int jq = (J0 >> 3) & 3;
        const int eh = J0 & 7;
        #pragma unroll
        for (int nt = 0; nt < 8; ++nt) {
            ushort4v pk;
            #pragma unroll
            for (int e = 0; e < 4; ++e) pk[e] = f2bf(acc[nt][e]);
            *reinterpret_cast<ushort4v*>(
                vfrag + (((size_t)(b * 64 + s) * 8 + nt) * 64 + (l15 | (jq << 4))) * 8 + eh) = pk;
        }
    } else {
        // ================= bias =================
        _Float16 (*st)[64][8] = (_Float16 (*)[64][8])smem;   // 8KB
        const int bid2 = bid - 256;
        const int iblk = bid2 >> 3;
        const int jch = bid2 & 7;
        const int i_l = t >> 4;
        const int o2 = t & 15;
        const int i = iblk * 16 + i_l;
        const int jbase = jch * 256 + o2 * 16;
        const float sc = scaler[0];

        const int* ap = adj + (size_t)i * NN + jbase;
        const float* dp = dist + (size_t)i * NN + jbase;
        int av[16]; float dv[16];
        *reinterpret_cast<int4*>(&av[0])  = *reinterpret_cast<const int4*>(ap);
        *reinterpret_cast<int4*>(&av[4])  = *reinterpret_cast<const int4*>(ap + 4);
        *reinterpret_cast<int4*>(&av[8])  = *reinterpret_cast<const int4*>(ap + 8);
        *reinterpret_cast<int4*>(&av[12]) = *reinterpret_cast<const int4*>(ap + 12);
        *reinterpret_cast<float4*>(&dv[0])  = *reinterpret_cast<const float4*>(dp);
        *reinterpret_cast<float4*>(&dv[4])  = *reinterpret_cast<const float4*>(dp + 4);
        *reinterpret_cast<float4*>(&dv[8])  = *reinterpret_cast<const float4*>(dp + 8);
        *reinterpret_cast<float4*>(&dv[12]) = *reinterpret_cast<const float4*>(dp + 12);

        #pragma unroll
        for (int u = 0; u < 2; ++u) {
            const int sl = (o2 * 2 + u) >> 2;
            const int jq = (o2 * 2 + u) & 3;
            f16x8 pk;
            #pragma unroll
            for (int e = 0; e < 8; ++e) {
                const int idx = u * 8 + e;
                float v = (av[idx] > 0) ? (-__log2f(dv[idx] + 1e-6f) * sc) : MASK_NEG_H;
                pk[e] = (_Float16)v;
            }
            *reinterpret_cast<f16x8*>(&st[sl][i_l | (jq << 4)][0]) = pk;
        }
        __syncthreads();

        const int w = t >> 6, lane = t & 63;
        #pragma unroll
        for (int sub = 0; sub < 2; ++sub) {
            const int fs = w * 2 + sub;
            *reinterpret_cast<f16x8*>(
                biasF + ((size_t)(iblk * 64 + jch * 8 + fs) * 64 + lane) * 8) =
                *reinterpret_cast<f16x8*>(&st[fs][lane][0]);
        }
    }
}

// ---------------------------------------------------------------------------
// Kernel C: R9 structure (best measured) + packed-fp16 score pipeline.
// Block = 64 rows x ALL 128 cols x 1 batch; grid 256; XCD = batch.
// 8 waves = 4 rt x 2 jh (1024 j = 32 K-steps). Score math x/lrelu/+bias in
// v_pk_*_f16 (2 elems/inst); exp in fp32 (range), P packed bf16.
// One barrier (jh combine) + epilogue.
// ---------------------------------------------------------------------------
__global__ __launch_bounds__(512) void k_attn(
    const unsigned short* __restrict__ vfrag, const float* __restrict__ siC,
    const _Float16* __restrict__ sjH, const _Float16* __restrict__ biasF,
    float* __restrict__ out)
{
    __shared__ __align__(16) float red[4][8][64][4];   // 32KB
    __shared__ float lp[2][4][16];                     // 512B

    const int t = threadIdx.x;
    const int lane = t & 63;
    const int w = t >> 6;          // 0..7
    const int rt = w & 3;          // 16-row tile
    const int jh = w >> 2;         // j half (1024 j)
    const int l15 = lane & 15;
    const int hi = lane >> 4;

    const int b = blockIdx.x & 7;   // XCD = batch
    const int rg = blockIdx.x >> 3; // 64-row group 0..31

    const int rowbase = rg * 64 + rt * 16;
    const _Float16 si_h = (_Float16)siC[b * NN + rowbase + l15];
    const f16x8 si8 = (f16x8)(si_h);
    const _Float16 slope = (_Float16)0.2f;

    const _Float16* sjp = sjH + b * NN + jh * 1024 + hi * 8;
    const _Float16* bp = biasF +
        ((size_t)((rg * 4 + rt) * 64 + jh * 32) * 64 + lane) * 8;
    const unsigned short* vp = vfrag +
        ((size_t)(b * 64 + jh * 32) * 8) * 512 + lane * 8;

    f32x4 acc[8];
    #pragma unroll
    for (int ct = 0; ct < 8; ++ct) acc[ct] = (f32x4)(0.f);
    float ls0 = 0.f;

    #pragma unroll 4
    for (int sl = 0; sl < 32; ++sl) {
        f16x8 sj8 = *reinterpret_cast<const f16x8*>(sjp + sl * 32);
        f16x8 bv = *reinterpret_cast<const f16x8*>(bp + sl * 512);
        f16x8 x = si8 + sj8;                                  // v_pk_add_f16
        f16x8 xl = __builtin_elementwise_max(x, x * slope);   // pk_mul + pk_max
        f16x8 y = xl + bv;                                    // v_pk_add_f16
        short8 pa;
        #pragma unroll
        for (int e = 0; e < 8; ++e) {
            float p = __builtin_amdgcn_exp2f((float)y[e]);
            ls0 += p;
            pa[e] = (short)f2bf(p);
        }
        const unsigned short* vs = vp + sl * 4096;
        #pragma unroll
        for (int ct = 0; ct < 8; ++ct) {
            const short8 bfr = *reinterpret_cast<const short8*>(vs + ct * 512);
            acc[ct] = __builtin_amdgcn_mfma_f32_16x16x32_bf16(pa, bfr, acc[ct], 0, 0, 0);
        }
    }

    // ---- combine jh halves ----
    ls0 += __shfl_xor(ls0, 16);
    ls0 += __shfl_xor(ls0, 32);
    if (lane < 16) lp[jh][rt][l15] = ls0;

    if (jh == 1) {
        #pragma unroll
        for (int ct = 0; ct < 8; ++ct)
            *reinterpret_cast<f32x4*>(&red[rt][ct][lane][0]) = acc[ct];
    }
    __syncthreads();
    if (jh == 0) {
        float linv[4];
        #pragma unroll
        for (int e = 0; e < 4; ++e) {
            const int rr = (hi << 2) + e;
            linv[e] = 1.0f / (lp[0][rt][rr] + lp[1][rt][rr]);
        }
        #pragma unroll
        for (int ct = 0; ct < 8; ++ct) {
            f32x4 o = acc[ct] + *reinterpret_cast<const f32x4*>(&red[rt][ct][lane][0]);
            const int col = ct * 16 + l15;
            #pragma unroll
            for (int e = 0; e < 4; ++e) {
                const int row = rowbase + (hi << 2) + e;
                float v = o[e] * linv[e];
                v = (v > 0.f) ? v : expm1f(v);
                out[(size_t)(b * NN + row) * NF + col] = v;
            }
        }
    }
}

extern "C" void kernel_launch(void* const* d_in, const int* in_sizes, int n_in,
                              void* d_out, int out_size, void* d_ws, size_t ws_size,
                              hipStream_t stream) {
    (void)in_sizes; (void)n_in; (void)out_size; (void)ws_size;
    const float* h      = (const float*)d_in[0];
    const int*   adj    = (const int*)d_in[1];
    const float* dist   = (const float*)d_in[2];
    const float* W      = (const float*)d_in[3];
    const float* a      = (const float*)d_in[4];
    const float* scaler = (const float*)d_in[5];
    float* out = (float*)d_out;

    char* ws = (char*)d_ws;
    unsigned short* vfrag = (unsigned short*)ws;                     // 4 MiB
    float* siC      = (float*)(ws + 4 * 1024 * 1024);                // 64 KiB
    _Float16* sjH   = (_Float16*)(ws + 4 * 1024 * 1024 + 65536);     // 32 KiB
    _Float16* biasF = (_Float16*)(ws + 4 * 1024 * 1024 + 2 * 65536); // 8 MiB

    k_pre<<<dim3(1280), dim3(256), 0, stream>>>(h, adj, dist, W, a, scaler,
                                                vfrag, siC, sjH, biasF);
    k_attn<<<dim3(NB * NN / 64), dim3(512), 0, stream>>>(vfrag, siC, sjH, biasF, out);
}

// Round 14
// 48.421 us; speedup vs baseline: 1.1509x; 1.0051x over previous
//
#include <hip/hip_runtime.h>
#include <hip/hip_bf16.h>

typedef __attribute__((ext_vector_type(4))) float f32x4;
typedef __attribute__((ext_vector_type(8))) short short8;
typedef __attribute__((ext_vector_type(4))) unsigned short ushort4v;
typedef _Float16 f16x8 __attribute__((ext_vector_type(8)));

#define NB 8
#define NN 2048
#define NF 128
#define LOG2E 1.4426950408889634f
#define MASK_NEG_H -60000.0f

static __device__ __forceinline__ unsigned short f2bf(float f) {
    union { __hip_bfloat16 b; unsigned short u; } cv;
    cv.b = __float2bfloat16(f);
    return cv.u;
}

// ---------------------------------------------------------------------------
// Kernel PRE (fused): blocks 0..255 = hprime (h@W -> vfrag B-frags, si/sj);
// blocks 256..1279 = bias -> biasF A-frags (fp16).
// ---------------------------------------------------------------------------
__global__ __launch_bounds__(256) void k_pre(
    const float* __restrict__ h, const int* __restrict__ adj,
    const float* __restrict__ dist, const float* __restrict__ W,
    const float* __restrict__ a, const float* __restrict__ scaler,
    unsigned short* __restrict__ vfrag, float* __restrict__ siC,
    float* __restrict__ sjC, _Float16* __restrict__ biasF)
{
    __shared__ __align__(16) unsigned char smem[34816];
    const int bid = blockIdx.x;
    const int t = threadIdx.x;

    if (bid < 256) {
        // ================= hprime =================
        unsigned char* WT = smem;                  // 32KB swizzled W^T bf16
        float* wa1 = (float*)(smem + 32768);
        float* wa2 = wa1 + NF;

        const int lane = t & 63;
        const int w = t >> 6;
        const int b = bid >> 5;
        const int i0 = (bid & 31) << 6;

        {
            const int f = t >> 1;
            const int c0 = (t & 1) << 6;
            float s1 = 0.f, s2 = 0.f;
            const float* wrow = W + f * NF + c0;
            const float* a1p = a + c0;
            const float* a2p = a + NF + c0;
            #pragma unroll 8
            for (int c = 0; c < 64; ++c) {
                float wv = wrow[c];
                s1 += wv * a1p[c];
                s2 += wv * a2p[c];
                int col = c0 + c;
                int dst = col * 256 + ((2 * f) ^ ((col & 15) << 4));
                *reinterpret_cast<unsigned short*>(&WT[dst]) = f2bf(wv);
            }
            s1 += __shfl_xor(s1, 1);
            s2 += __shfl_xor(s2, 1);
            if ((t & 1) == 0) { wa1[f] = s1 * LOG2E; wa2[f] = s2 * LOG2E; }
        }
        __syncthreads();

        const int l15 = lane & 15;
        const int arow = i0 + w * 16 + l15;
        const int kofs = (lane >> 4) << 3;
        const float* hrow = h + (size_t)(b * NN + arow) * NF + kofs;
        const int swz = l15 << 4;

        f32x4 acc[8];
        #pragma unroll
        for (int nt = 0; nt < 8; ++nt) acc[nt] = (f32x4)(0.f);
        float s1 = 0.f, s2 = 0.f;

        #pragma unroll
        for (int k0 = 0; k0 < NF; k0 += 32) {
            f32x4 h0 = *reinterpret_cast<const f32x4*>(hrow + k0);
            f32x4 h1 = *reinterpret_cast<const f32x4*>(hrow + k0 + 4);
            f32x4 w1lo = *reinterpret_cast<const f32x4*>(&wa1[k0 + kofs]);
            f32x4 w1hi = *reinterpret_cast<const f32x4*>(&wa1[k0 + kofs + 4]);
            f32x4 w2lo = *reinterpret_cast<const f32x4*>(&wa2[k0 + kofs]);
            f32x4 w2hi = *reinterpret_cast<const f32x4*>(&wa2[k0 + kofs + 4]);
            short8 af;
            #pragma unroll
            for (int e = 0; e < 4; ++e) {
                s1 += h0[e] * w1lo[e] + h1[e] * w1hi[e];
                s2 += h0[e] * w2lo[e] + h1[e] * w2hi[e];
                af[e]     = (short)f2bf(h0[e]);
                af[4 + e] = (short)f2bf(h1[e]);
            }
            const int ib = (2 * (k0 + kofs)) ^ swz;
            #pragma unroll
            for (int nt = 0; nt < 8; ++nt) {
                short8 bf8 = *reinterpret_cast<short8*>(&WT[(nt * 16 + l15) * 256 + ib]);
                acc[nt] = __builtin_amdgcn_mfma_f32_16x16x32_bf16(af, bf8, acc[nt], 0, 0, 0);
            }
        }

        s1 += __shfl_xor(s1, 16); s1 += __shfl_xor(s1, 32);
        s2 += __shfl_xor(s2, 16); s2 += __shfl_xor(s2, 32);
        if (lane < 16) {
            siC[b * NN + arow] = s1;
            sjC[b * NN + arow] = s2;
        }

        const int J0 = i0 + w * 16 + ((lane >> 4) << 2);
        const int s = J0 >> 5;
        const int jq = (J0 >> 3) & 3;
        const int eh = J0 & 7;
        #pragma unroll
        for (int nt = 0; nt < 8; ++nt) {
            ushort4v pk;
            #pragma unroll
            for (int e = 0; e < 4; ++e) pk[e] = f2bf(acc[nt][e]);
            *reinterpret_cast<ushort4v*>(
                vfrag + (((size_t)(b * 64 + s) * 8 + nt) * 64 + (l15 | (jq << 4))) * 8 + eh) = pk;
        }
    } else {
        // ================= bias =================
        _Float16 (*st)[64][8] = (_Float16 (*)[64][8])smem;   // 8KB
        const int bid2 = bid - 256;
        const int iblk = bid2 >> 3;
        const int jch = bid2 & 7;
        const int i_l = t >> 4;
        const int o2 = t & 15;
        const int i = iblk * 16 + i_l;
        const int jbase = jch * 256 + o2 * 16;
        const float sc = scaler[0];

        const int* ap = adj + (size_t)i * NN + jbase;
        const float* dp = dist + (size_t)i * NN + jbase;
        int av[16]; float dv[16];
        *reinterpret_cast<int4*>(&av[0])  = *reinterpret_cast<const int4*>(ap);
        *reinterpret_cast<int4*>(&av[4])  = *reinterpret_cast<const int4*>(ap + 4);
        *reinterpret_cast<int4*>(&av[8])  = *reinterpret_cast<const int4*>(ap + 8);
        *reinterpret_cast<int4*>(&av[12]) = *reinterpret_cast<const int4*>(ap + 12);
        *reinterpret_cast<float4*>(&dv[0])  = *reinterpret_cast<const float4*>(dp);
        *reinterpret_cast<float4*>(&dv[4])  = *reinterpret_cast<const float4*>(dp + 4);
        *reinterpret_cast<float4*>(&dv[8])  = *reinterpret_cast<const float4*>(dp + 8);
        *reinterpret_cast<float4*>(&dv[12]) = *reinterpret_cast<const float4*>(dp + 12);

        #pragma unroll
        for (int u = 0; u < 2; ++u) {
            const int sl = (o2 * 2 + u) >> 2;
            const int jq = (o2 * 2 + u) & 3;
            f16x8 pk;
            #pragma unroll
            for (int e = 0; e < 8; ++e) {
                const int idx = u * 8 + e;
                float v = (av[idx] > 0) ? (-__log2f(dv[idx] + 1e-6f) * sc) : MASK_NEG_H;
                pk[e] = (_Float16)v;
            }
            *reinterpret_cast<f16x8*>(&st[sl][i_l | (jq << 4)][0]) = pk;
        }
        __syncthreads();

        const int w = t >> 6, lane = t & 63;
        #pragma unroll
        for (int sub = 0; sub < 2; ++sub) {
            const int fs = w * 2 + sub;
            *reinterpret_cast<f16x8*>(
                biasF + ((size_t)(iblk * 64 + jch * 8 + fs) * 64 + lane) * 8) =
                *reinterpret_cast<f16x8*>(&st[fs][lane][0]);
        }
    }
}

// ---------------------------------------------------------------------------
// Kernel C: barrier-free main loop + REGISTER double-buffer V prefetch.
// Block = 32 rows x 128 cols; grid 512 = 2 blocks/CU, 16 waves/CU (4/SIMD).
// 8 waves = 2 rt (16-row tiles) x 4 jh (512-j strips, 16 K-steps).
// va/vb (static-indexed, manual 2-step loop) give every V load one full
// compute-step (~400-800cy wall) to land. acc[8]+va+vb ~ 125 VGPR, cap 128.
// Tail: 3-barrier tree over 4 jh partials (32KB LDS) + 2-wave epilogue.
// XCD = batch: V[b] (512KB) L2-pinned.
// ---------------------------------------------------------------------------
__global__ __launch_bounds__(512, 4) void k_attn(
    const unsigned short* __restrict__ vfrag, const float* __restrict__ siC,
    const float* __restrict__ sjC, const _Float16* __restrict__ biasF,
    float* __restrict__ out)
{
    __shared__ __align__(16) f32x4 red[4][512];   // 4 x 8KB = 32KB
    __shared__ float lp[4][2][16];                // 512B

    const int t = threadIdx.x;
    const int lane = t & 63;
    const int w = t >> 6;          // 0..7
    const int rt = w & 1;          // 16-row tile
    const int jh = w >> 1;         // 512-j strip 0..3
    const int l15 = lane & 15;
    const int hi = lane >> 4;

    const int b = blockIdx.x & 7;   // XCD = batch
    const int rg = blockIdx.x >> 3; // 32-row group 0..63

    const int rowbase = rg * 32 + rt * 16;
    const float si0 = siC[b * NN + rowbase + l15];

    const float* sjp = sjC + b * NN + jh * 512 + hi * 8;
    const _Float16* bp = biasF +
        ((size_t)((rg * 2 + rt) * 64 + jh * 16) * 64 + lane) * 8;
    const unsigned short* vp = vfrag +
        ((size_t)(b * 64 + jh * 16) * 8) * 512 + lane * 8;

    f32x4 acc[8];
    #pragma unroll
    for (int ct = 0; ct < 8; ++ct) acc[ct] = (f32x4)(0.f);
    float ls0 = 0.f;

    short8 va[8], vb[8];
    #pragma unroll
    for (int ct = 0; ct < 8; ++ct)
        va[ct] = *reinterpret_cast<const short8*>(vp + ct * 512);

#define SCORE_MFMA(S, VBUF)                                                    \
    {                                                                          \
        f32x4 sj0 = *reinterpret_cast<const f32x4*>(sjp + (S) * 32);           \
        f32x4 sj1 = *reinterpret_cast<const f32x4*>(sjp + (S) * 32 + 4);       \
        f16x8 bv = *reinterpret_cast<const f16x8*>(bp + (S) * 512);            \
        short8 pa;                                                             \
        _Pragma("unroll")                                                      \
        for (int e = 0; e < 8; ++e) {                                          \
            const float sjv = (e < 4) ? sj0[e] : sj1[e - 4];                   \
            float x = si0 + sjv;                                               \
            x = fmaxf(x, 0.2f * x) + (float)bv[e];                             \
            float p = __builtin_amdgcn_exp2f(x);                               \
            ls0 += p;                                                          \
            pa[e] = (short)f2bf(p);                                            \
        }                                                                      \
        _Pragma("unroll")                                                      \
        for (int ct = 0; ct < 8; ++ct)                                         \
            acc[ct] = __builtin_amdgcn_mfma_f32_16x16x32_bf16(                 \
                pa, VBUF[ct], acc[ct], 0, 0, 0);                               \
    }

    for (int sl = 0; sl < 16; sl += 2) {
        {   // prefetch step sl+1 into vb (issued BEFORE computing sl)
            const unsigned short* vn = vp + (sl + 1) * 4096;
            #pragma unroll
            for (int ct = 0; ct < 8; ++ct)
                vb[ct] = *reinterpret_cast<const short8*>(vn + ct * 512);
        }
        SCORE_MFMA(sl, va)
        if (sl + 2 < 16) {   // prefetch step sl+2 into va
            const unsigned short* vn = vp + (sl + 2) * 4096;
            #pragma unroll
            for (int ct = 0; ct < 8; ++ct)
                va[ct] = *reinterpret_cast<const short8*>(vn + ct * 512);
        }
        SCORE_MFMA(sl + 1, vb)
    }
#undef SCORE_MFMA

    // ---- combine 4 jh partials ----
    ls0 += __shfl_xor(ls0, 16);
    ls0 += __shfl_xor(ls0, 32);
    if (lane < 16) lp[jh][rt][l15] = ls0;

#define WACC(buf) { _Pragma("unroll") for (int ct = 0; ct < 8; ++ct)       \
        red[buf][ct * 64 + lane] = acc[ct]; }
#define AACC(buf) { _Pragma("unroll") for (int ct = 0; ct < 8; ++ct)       \
        acc[ct] += red[buf][ct * 64 + lane]; }

    if (jh == 1) WACC(rt * 2)
    if (jh == 3) WACC(rt * 2 + 1)
    __syncthreads();
    if (jh == 0) AACC(rt * 2)
    if (jh == 2) AACC(rt * 2 + 1)
    __syncthreads();
    if (jh == 2) WACC(rt * 2)
    __syncthreads();
    if (jh == 0) {
        AACC(rt * 2)
        float linv[4];
        #pragma unroll
        for (int e = 0; e < 4; ++e) {
            const int rr = (hi << 2) + e;
            linv[e] = 1.0f / (lp[0][rt][rr] + lp[1][rt][rr]
                            + lp[2][rt][rr] + lp[3][rt][rr]);
        }
        #pragma unroll
        for (int ct = 0; ct < 8; ++ct) {
            const int col = ct * 16 + l15;
            #pragma unroll
            for (int e = 0; e < 4; ++e) {
                const int row = rowbase + (hi << 2) + e;
                float v = acc[ct][e] * linv[e];
                v = (v > 0.f) ? v : expm1f(v);
                out[(size_t)(b * NN + row) * NF + col] = v;
            }
        }
    }
#undef WACC
#undef AACC
}

extern "C" void kernel_launch(void* const* d_in, const int* in_sizes, int n_in,
                              void* d_out, int out_size, void* d_ws, size_t ws_size,
                              hipStream_t stream) {
    (void)in_sizes; (void)n_in; (void)out_size; (void)ws_size;
    const float* h      = (const float*)d_in[0];
    const int*   adj    = (const int*)d_in[1];
    const float* dist   = (const float*)d_in[2];
    const float* W      = (const float*)d_in[3];
    const float* a      = (const float*)d_in[4];
    const float* scaler = (const float*)d_in[5];
    float* out = (float*)d_out;

    char* ws = (char*)d_ws;
    unsigned short* vfrag = (unsigned short*)ws;                     // 4 MiB
    float* siC      = (float*)(ws + 4 * 1024 * 1024);                // 64 KiB
    float* sjC      = (float*)(ws + 4 * 1024 * 1024 + 65536);        // 64 KiB
    _Float16* biasF = (_Float16*)(ws + 4 * 1024 * 1024 + 2 * 65536); // 8 MiB

    k_pre<<<dim3(1280), dim3(256), 0, stream>>>(h, adj, dist, W, a, scaler,
                                                vfrag, siC, sjC, biasF);
    k_attn<<<dim3(NB * NN / 32), dim3(512), 0, stream>>>(vfrag, siC, sjC, biasF, out);
}

// Round 15
// 43.454 us; speedup vs baseline: 1.2825x; 1.1143x over previous
//
#include <hip/hip_runtime.h>
#include <hip/hip_bf16.h>

typedef __attribute__((ext_vector_type(4))) float f32x4;
typedef __attribute__((ext_vector_type(8))) short short8;
typedef __attribute__((ext_vector_type(4))) unsigned short ushort4v;
typedef _Float16 f16x8 __attribute__((ext_vector_type(8)));

#define NB 8
#define NN 2048
#define NF 128
#define LOG2E 1.4426950408889634f
#define MASK_NEG_H -60000.0f

static __device__ __forceinline__ unsigned short f2bf(float f) {
    union { __hip_bfloat16 b; unsigned short u; } cv;
    cv.b = __float2bfloat16(f);
    return cv.u;
}

static __device__ __forceinline__ void gload_lds16(const void* g, void* l) {
    __builtin_amdgcn_global_load_lds(
        (const __attribute__((address_space(1))) unsigned int*)g,
        (__attribute__((address_space(3))) unsigned int*)l, 16, 0, 0);
}

// ---------------------------------------------------------------------------
// Kernel PRE (fused): blocks 0..255 = hprime (h@W -> vfrag B-frags, si/sj);
// blocks 256..1279 = bias -> biasF A-frags (fp16).
// ---------------------------------------------------------------------------
__global__ __launch_bounds__(256) void k_pre(
    const float* __restrict__ h, const int* __restrict__ adj,
    const float* __restrict__ dist, const float* __restrict__ W,
    const float* __restrict__ a, const float* __restrict__ scaler,
    unsigned short* __restrict__ vfrag, float* __restrict__ siC,
    float* __restrict__ sjC, _Float16* __restrict__ biasF)
{
    __shared__ __align__(16) unsigned char smem[34816];
    const int bid = blockIdx.x;
    const int t = threadIdx.x;

    if (bid < 256) {
        unsigned char* WT = smem;                  // 32KB swizzled W^T bf16
        float* wa1 = (float*)(smem + 32768);
        float* wa2 = wa1 + NF;

        const int lane = t & 63;
        const int w = t >> 6;
        const int b = bid >> 5;
        const int i0 = (bid & 31) << 6;

        {
            const int f = t >> 1;
            const int c0 = (t & 1) << 6;
            float s1 = 0.f, s2 = 0.f;
            const float* wrow = W + f * NF + c0;
            const float* a1p = a + c0;
            const float* a2p = a + NF + c0;
            #pragma unroll 8
            for (int c = 0; c < 64; ++c) {
                float wv = wrow[c];
                s1 += wv * a1p[c];
                s2 += wv * a2p[c];
                int col = c0 + c;
                int dst = col * 256 + ((2 * f) ^ ((col & 15) << 4));
                *reinterpret_cast<unsigned short*>(&WT[dst]) = f2bf(wv);
            }
            s1 += __shfl_xor(s1, 1);
            s2 += __shfl_xor(s2, 1);
            if ((t & 1) == 0) { wa1[f] = s1 * LOG2E; wa2[f] = s2 * LOG2E; }
        }
        __syncthreads();

        const int l15 = lane & 15;
        const int arow = i0 + w * 16 + l15;
        const int kofs = (lane >> 4) << 3;
        const float* hrow = h + (size_t)(b * NN + arow) * NF + kofs;
        const int swz = l15 << 4;

        f32x4 acc[8];
        #pragma unroll
        for (int nt = 0; nt < 8; ++nt) acc[nt] = (f32x4)(0.f);
        float s1 = 0.f, s2 = 0.f;

        #pragma unroll
        for (int k0 = 0; k0 < NF; k0 += 32) {
            f32x4 h0 = *reinterpret_cast<const f32x4*>(hrow + k0);
            f32x4 h1 = *reinterpret_cast<const f32x4*>(hrow + k0 + 4);
            f32x4 w1lo = *reinterpret_cast<const f32x4*>(&wa1[k0 + kofs]);
            f32x4 w1hi = *reinterpret_cast<const f32x4*>(&wa1[k0 + kofs + 4]);
            f32x4 w2lo = *reinterpret_cast<const f32x4*>(&wa2[k0 + kofs]);
            f32x4 w2hi = *reinterpret_cast<const f32x4*>(&wa2[k0 + kofs + 4]);
            short8 af;
            #pragma unroll
            for (int e = 0; e < 4; ++e) {
                s1 += h0[e] * w1lo[e] + h1[e] * w1hi[e];
                s2 += h0[e] * w2lo[e] + h1[e] * w2hi[e];
                af[e]     = (short)f2bf(h0[e]);
                af[4 + e] = (short)f2bf(h1[e]);
            }
            const int ib = (2 * (k0 + kofs)) ^ swz;
            #pragma unroll
            for (int nt = 0; nt < 8; ++nt) {
                short8 bf8 = *reinterpret_cast<short8*>(&WT[(nt * 16 + l15) * 256 + ib]);
                acc[nt] = __builtin_amdgcn_mfma_f32_16x16x32_bf16(af, bf8, acc[nt], 0, 0, 0);
            }
        }

        s1 += __shfl_xor(s1, 16); s1 += __shfl_xor(s1, 32);
        s2 += __shfl_xor(s2, 16); s2 += __shfl_xor(s2, 32);
        if (lane < 16) {
            siC[b * NN + arow] = s1;
            sjC[b * NN + arow] = s2;
        }

        const int J0 = i0 + w * 16 + ((lane >> 4) << 2);
        const int s = J0 >> 5;
        const int jq = (J0 >> 3) & 3;
        const int eh = J0 & 7;
        #pragma unroll
        for (int nt = 0; nt < 8; ++nt) {
            ushort4v pk;
            #pragma unroll
            for (int e = 0; e < 4; ++e) pk[e] = f2bf(acc[nt][e]);
            *reinterpret_cast<ushort4v*>(
                vfrag + (((size_t)(b * 64 + s) * 8 + nt) * 64 + (l15 | (jq << 4))) * 8 + eh) = pk;
        }
    } else {
        _Float16 (*st)[64][8] = (_Float16 (*)[64][8])smem;   // 8KB
        const int bid2 = bid - 256;
        const int iblk = bid2 >> 3;
        const int jch = bid2 & 7;
        const int i_l = t >> 4;
        const int o2 = t & 15;
        const int i = iblk * 16 + i_l;
        const int jbase = jch * 256 + o2 * 16;
        const float sc = scaler[0];

        const int* ap = adj + (size_t)i * NN + jbase;
        const float* dp = dist + (size_t)i * NN + jbase;
        int av[16]; float dv[16];
        *reinterpret_cast<int4*>(&av[0])  = *reinterpret_cast<const int4*>(ap);
        *reinterpret_cast<int4*>(&av[4])  = *reinterpret_cast<const int4*>(ap + 4);
        *reinterpret_cast<int4*>(&av[8])  = *reinterpret_cast<const int4*>(ap + 8);
        *reinterpret_cast<int4*>(&av[12]) = *reinterpret_cast<const int4*>(ap + 12);
        *reinterpret_cast<float4*>(&dv[0])  = *reinterpret_cast<const float4*>(dp);
        *reinterpret_cast<float4*>(&dv[4])  = *reinterpret_cast<const float4*>(dp + 4);
        *reinterpret_cast<float4*>(&dv[8])  = *reinterpret_cast<const float4*>(dp + 8);
        *reinterpret_cast<float4*>(&dv[12]) = *reinterpret_cast<const float4*>(dp + 12);

        #pragma unroll
        for (int u = 0; u < 2; ++u) {
            const int sl = (o2 * 2 + u) >> 2;
            const int jq = (o2 * 2 + u) & 3;
            f16x8 pk;
            #pragma unroll
            for (int e = 0; e < 8; ++e) {
                const int idx = u * 8 + e;
                float v = (av[idx] > 0) ? (-__log2f(dv[idx] + 1e-6f) * sc) : MASK_NEG_H;
                pk[e] = (_Float16)v;
            }
            *reinterpret_cast<f16x8*>(&st[sl][i_l | (jq << 4)][0]) = pk;
        }
        __syncthreads();

        const int w = t >> 6, lane = t & 63;
        #pragma unroll
        for (int sub = 0; sub < 2; ++sub) {
            const int fs = w * 2 + sub;
            *reinterpret_cast<f16x8*>(
                biasF + ((size_t)(iblk * 64 + jch * 8 + fs) * 64 + lane) * 8) =
                *reinterpret_cast<f16x8*>(&st[fs][lane][0]);
        }
    }
}

// ---------------------------------------------------------------------------
// Kernel C: T3/T4-style counted pipeline. Block = 64 rows x 128 cols, grid
// 256 (XCD = batch). V staged via global_load_lds into 3x32KB LDS tiles,
// 2 tiles ahead; per-tile asm vmcnt(10) + raw s_barrier (vmcnt NEVER 0 in
// the loop). bias/sj reg-prefetched one tile ahead, ISSUED BEFORE the stage
// so compiler waits stay counted. 8 waves = 4 rt x 2 jh. Combine reuses buf0.
// ---------------------------------------------------------------------------
__global__ __launch_bounds__(512) void k_attn(
    const unsigned short* __restrict__ vfrag, const float* __restrict__ siC,
    const float* __restrict__ sjC, const _Float16* __restrict__ biasF,
    float* __restrict__ out)
{
    __shared__ __align__(16) unsigned char vbuf[3][32768];  // 96KB
    __shared__ float lp[2][4][16];

    const int t = threadIdx.x;
    const int lane = t & 63;
    const int w = t >> 6;          // 0..7
    const int rt = w & 3;          // 16-row tile
    const int jh = w >> 2;         // 64-j half of each 128-j tile
    const int l15 = lane & 15;
    const int hi = lane >> 4;

    const int b = blockIdx.x & 7;   // XCD = batch
    const int rg = blockIdx.x >> 3; // 64-row group 0..31

    const int rowbase = rg * 64 + rt * 16;
    const float si0 = siC[b * NN + rowbase + l15];

    // global source for staging: chunk c of tile tl, this thread's 16B
    const unsigned short* vsrc = vfrag + (size_t)b * 262144 + w * 512 + lane * 8;
    const int ldst = w * 1024;     // + c*8192, lane*16 implicit

    const _Float16* bp = biasF + ((size_t)((rg * 4 + rt) * 64) * 64 + lane) * 8;
    const float* sjb = sjC + b * NN + hi * 8;

    f32x4 acc[8];
    #pragma unroll
    for (int ct = 0; ct < 8; ++ct) acc[ct] = (f32x4)(0.f);
    float ls0 = 0.f;

#define STAGE(TL, BUF)                                                        \
    { const unsigned short* gs = vsrc + (TL) * 16384;                         \
      unsigned char* lb = &vbuf[BUF][ldst];                                   \
      gload_lds16(gs,         lb);                                            \
      gload_lds16(gs + 4096,  lb + 8192);                                     \
      gload_lds16(gs + 8192,  lb + 16384);                                    \
      gload_lds16(gs + 12288, lb + 24576); }

    // score-input regs, prefetched one tile ahead (q=0 -> A, q=1 -> B)
    f32x4 sjA0, sjA1, sjB0, sjB1;
    f16x8 bvA, bvB;

#define PREFETCH_SB(TL)                                                       \
    { const int sA = (TL) * 4 + jh * 2;                                       \
      sjA0 = *reinterpret_cast<const f32x4*>(sjb + sA * 32);                  \
      sjA1 = *reinterpret_cast<const f32x4*>(sjb + sA * 32 + 4);              \
      bvA  = *reinterpret_cast<const f16x8*>(bp + sA * 512);                  \
      sjB0 = *reinterpret_cast<const f32x4*>(sjb + sA * 32 + 32);             \
      sjB1 = *reinterpret_cast<const f32x4*>(sjb + sA * 32 + 36);             \
      bvB  = *reinterpret_cast<const f16x8*>(bp + sA * 512 + 512); }

#define QSTEP(SJ0, SJ1, BV, LSL, BUF)                                         \
    { short8 pa;                                                              \
      _Pragma("unroll")                                                       \
      for (int e = 0; e < 8; ++e) {                                           \
          const float sjv = (e < 4) ? SJ0[e] : SJ1[e - 4];                    \
          float x = si0 + sjv;                                                \
          x = fmaxf(x, 0.2f * x) + (float)BV[e];                              \
          float p = __builtin_amdgcn_exp2f(x);                                \
          ls0 += p;                                                           \
          pa[e] = (short)f2bf(p);                                             \
      }                                                                       \
      _Pragma("unroll")                                                       \
      for (int ct = 0; ct < 8; ++ct) {                                        \
          const short8 bfr = *reinterpret_cast<const short8*>(                \
              &vbuf[BUF][((LSL) * 8 + ct) * 1024 + lane * 16]);               \
          acc[ct] = __builtin_amdgcn_mfma_f32_16x16x32_bf16(pa, bfr, acc[ct], 0, 0, 0); \
      } }

    // prologue: gload(0), bias(0), gload(1)  [order matters for vmcnt counting]
    STAGE(0, 0)
    PREFETCH_SB(0)
    STAGE(1, 1)

    for (int tl = 0; tl < 15; ++tl) {
        const int buf = tl % 3;
        // outstanding (oldest first): gload(tl)x4, bias(tl)x6, gload(tl+1)x4
        asm volatile("s_waitcnt vmcnt(10)" ::: "memory");
        __builtin_amdgcn_s_barrier();
        QSTEP(sjA0, sjA1, bvA, jh * 2, buf)
        QSTEP(sjB0, sjB1, bvB, jh * 2 + 1, buf)
        PREFETCH_SB(tl + 1)
        if (tl + 2 < 16) STAGE(tl + 2, (tl + 2) % 3)
        __builtin_amdgcn_s_barrier();
    }
    {   // peeled tl = 15: outstanding = gload(15)x4, bias(15)x6
        asm volatile("s_waitcnt vmcnt(6)" ::: "memory");
        __builtin_amdgcn_s_barrier();
        QSTEP(sjA0, sjA1, bvA, jh * 2, 0)
        QSTEP(sjB0, sjB1, bvB, jh * 2 + 1, 0)
    }
#undef STAGE
#undef PREFETCH_SB
#undef QSTEP

    // ---- combine jh halves (reuse vbuf[1] as fp32 red buffer) ----
    ls0 += __shfl_xor(ls0, 16);
    ls0 += __shfl_xor(ls0, 32);
    if (lane < 16) lp[jh][rt][l15] = ls0;
    __syncthreads();

    if (jh == 1) {
        #pragma unroll
        for (int ct = 0; ct < 8; ++ct)
            *reinterpret_cast<f32x4*>(&vbuf[1][(rt * 8 + ct) * 1024 + lane * 16]) = acc[ct];
    }
    __syncthreads();
    if (jh == 0) {
        float linv[4];
        #pragma unroll
        for (int e = 0; e < 4; ++e) {
            const int rr = (hi << 2) + e;
            linv[e] = 1.0f / (lp[0][rt][rr] + lp[1][rt][rr]);
        }
        #pragma unroll
        for (int ct = 0; ct < 8; ++ct) {
            f32x4 o = acc[ct] + *reinterpret_cast<const f32x4*>(
                &vbuf[1][(rt * 8 + ct) * 1024 + lane * 16]);
            const int col = ct * 16 + l15;
            #pragma unroll
            for (int e = 0; e < 4; ++e) {
                const int row = rowbase + (hi << 2) + e;
                float v = o[e] * linv[e];
                v = (v > 0.f) ? v : expm1f(v);
                out[(size_t)(b * NN + row) * NF + col] = v;
            }
        }
    }
}

extern "C" void kernel_launch(void* const* d_in, const int* in_sizes, int n_in,
                              void* d_out, int out_size, void* d_ws, size_t ws_size,
                              hipStream_t stream) {
    (void)in_sizes; (void)n_in; (void)out_size; (void)ws_size;
    const float* h      = (const float*)d_in[0];
    const int*   adj    = (const int*)d_in[1];
    const float* dist   = (const float*)d_in[2];
    const float* W      = (const float*)d_in[3];
    const float* a      = (const float*)d_in[4];
    const float* scaler = (const float*)d_in[5];
    float* out = (float*)d_out;

    char* ws = (char*)d_ws;
    unsigned short* vfrag = (unsigned short*)ws;                     // 4 MiB
    float* siC      = (float*)(ws + 4 * 1024 * 1024);                // 64 KiB
    float* sjC      = (float*)(ws + 4 * 1024 * 1024 + 65536);        // 64 KiB
    _Float16* biasF = (_Float16*)(ws + 4 * 1024 * 1024 + 2 * 65536); // 8 MiB

    k_pre<<<dim3(1280), dim3(256), 0, stream>>>(h, adj, dist, W, a, scaler,
                                                vfrag, siC, sjC, biasF);
    k_attn<<<dim3(NB * NN / 64), dim3(512), 0, stream>>>(vfrag, siC, sjC, biasF, out);
}